// Round 1
// baseline (14142.120 us; speedup 1.0000x reference)
//
#include <hip/hip_runtime.h>

#define Bv 128
#define Tv 256
#define Dv 512
#define Hv 1024
#define NG 4096   // 4*H

typedef __bf16 bf16x8 __attribute__((ext_vector_type(8)));
typedef float  f32x4  __attribute__((ext_vector_type(4)));
typedef unsigned short u16;

__device__ __forceinline__ u16 f2bf(float f){
  unsigned u = __float_as_uint(f);
  u = (u + 0x7FFFu + ((u >> 16) & 1u)) >> 16;
  return (u16)u;
}
__device__ __forceinline__ float bf2f(u16 b){ return __uint_as_float(((unsigned)b) << 16); }
__device__ __forceinline__ float fsig(float x){ return 1.0f / (1.0f + __expf(-x)); }
__device__ __forceinline__ float ftanh(float x){ return 1.0f - 2.0f / (1.0f + __expf(2.0f * x)); }

// ---------------- setup kernels ----------------

// fp32 -> bf16, 4 elements/thread
__global__ void cvt_f32_bf16(const float* __restrict__ src, u16* __restrict__ dst, int n4){
  int i = blockIdx.x * 256 + threadIdx.x;
  if (i < n4){
    float4 v = ((const float4*)src)[i];
    ushort4 o;
    o.x = f2bf(v.x); o.y = f2bf(v.y); o.z = f2bf(v.z); o.w = f2bf(v.w);
    ((ushort4*)dst)[i] = o;
  }
}

// Pack 4 gate matrices [K, 1024] fp32 into MFMA B-frag layout:
// out index o = ((ntile*KT + ktile)*64 + lane)*8 + j
// element = W[gate][k*1024 + col], k = ktile*32 + (lane>>4)*8 + j,
// n = ntile*16 + (lane&15), gate = n>>10, col = n&1023.
__global__ void pack_b(const float* __restrict__ Wi, const float* __restrict__ Wf,
                       const float* __restrict__ Wg, const float* __restrict__ Wo,
                       u16* __restrict__ dst, int KTm1, int ntshift){
  int o = blockIdx.x * 256 + threadIdx.x;
  int j = o & 7;
  int lane = (o >> 3) & 63;
  int kt = (o >> 9) & KTm1;
  int ntile = o >> ntshift;
  int k = kt * 32 + ((lane >> 4) << 3) + j;
  int n = ntile * 16 + (lane & 15);
  const float* src = (n < 1024) ? Wi : (n < 2048) ? Wf : (n < 3072) ? Wg : Wo;
  dst[o] = f2bf(src[k * 1024 + (n & 1023)]);
}

__global__ void pack_bias(const float* __restrict__ bi, const float* __restrict__ bfp,
                          const float* __restrict__ bg, const float* __restrict__ bo,
                          float* __restrict__ dst){
  int n = blockIdx.x * 256 + threadIdx.x;   // 0..4095
  const float* s = (n < 1024) ? bi : (n < 2048) ? bfp : (n < 3072) ? bg : bo;
  dst[n] = s[n & 1023];
}

// ---------------- pre-GEMM: Z = A @ Wpacked + bias ----------------
// A: bf16 row-major [32768, K]; Z: bf16 [32768, 4096]
// block: 4 waves; wave w handles mtiles {2w, 2w+1} of a 128-row block-row,
// 4 consecutive ntiles (64 cols). grid = (4096/64, 32768/128)
__global__ __launch_bounds__(256) void pregemm(const u16* __restrict__ A,
                                               const u16* __restrict__ Wp,
                                               const float* __restrict__ bias,
                                               u16* __restrict__ Z,
                                               int K){
  int w = threadIdx.x >> 6, lane = threadIdx.x & 63;
  int quad = lane >> 4, l15 = lane & 15;
  int nblk = blockIdx.x;   // 0..63
  int mblk = blockIdx.y;   // 0..255
  int KT = K >> 5;
  const u16* Arow0 = A + (size_t)(mblk * 128 + w * 32 + l15) * K;
  const u16* Arow1 = Arow0 + (size_t)16 * K;
  f32x4 acc[2][4] = {};
  for (int kt = 0; kt < KT; ++kt){
    int kofs = kt * 32 + quad * 8;
    bf16x8 a0 = *(const bf16x8*)(Arow0 + kofs);
    bf16x8 a1 = *(const bf16x8*)(Arow1 + kofs);
#pragma unroll
    for (int g = 0; g < 4; ++g){
      int ntile = nblk * 4 + g;
      bf16x8 b = *(const bf16x8*)(Wp + ((size_t)(ntile * KT + kt) * 64 + lane) * 8);
      acc[0][g] = __builtin_amdgcn_mfma_f32_16x16x32_bf16(a0, b, acc[0][g], 0, 0, 0);
      acc[1][g] = __builtin_amdgcn_mfma_f32_16x16x32_bf16(a1, b, acc[1][g], 0, 0, 0);
    }
  }
#pragma unroll
  for (int mt = 0; mt < 2; ++mt){
    int rowbase = mblk * 128 + w * 32 + mt * 16 + quad * 4;
#pragma unroll
    for (int g = 0; g < 4; ++g){
      int n = (nblk * 4 + g) * 16 + l15;
      float bv = bias[n];
#pragma unroll
      for (int r = 0; r < 4; ++r){
        Z[(size_t)(rowbase + r) * NG + n] = f2bf(acc[mt][g][r] + bv);
      }
    }
  }
}

// ---------------- recurrent step ----------------
// G = hprev @ Ucat + Z_t; gates; c,h update.
// grid = (64 j-tiles, 2 m-halves), block = 256 (4 waves).
// wave mtile = half*4 + w (16 batch rows); wave covers gate ntiles {g*64 + jt}.
__global__ __launch_bounds__(256) void lstm_step(const u16* __restrict__ hprev,
                                                 const u16* __restrict__ Up,
                                                 const u16* __restrict__ Zt,   // Z + t*NG
                                                 float* __restrict__ cbuf,
                                                 u16* __restrict__ hcur,
                                                 u16* __restrict__ dst_bf,
                                                 float* __restrict__ out_h,
                                                 float* __restrict__ out_c,
                                                 int t, int last){
  int w = threadIdx.x >> 6, lane = threadIdx.x & 63;
  int quad = lane >> 4, l15 = lane & 15;
  int jt = blockIdx.x;            // 0..63
  int mtile = blockIdx.y * 4 + w; // 0..7
  const u16* Arow = hprev + (size_t)(mtile * 16 + l15) * Hv;
  f32x4 acc[4] = {};
#pragma unroll 4
  for (int kt = 0; kt < 32; ++kt){
    bf16x8 a = *(const bf16x8*)(Arow + kt * 32 + quad * 8);
#pragma unroll
    for (int g = 0; g < 4; ++g){
      int ntile = g * 64 + jt;
      bf16x8 b = *(const bf16x8*)(Up + ((size_t)(ntile * 32 + kt) * 64 + lane) * 8);
      acc[g] = __builtin_amdgcn_mfma_f32_16x16x32_bf16(a, b, acc[g], 0, 0, 0);
    }
  }
  int j = jt * 16 + l15;
#pragma unroll
  for (int r = 0; r < 4; ++r){
    int brow = mtile * 16 + quad * 4 + r;
    const u16* zrow = Zt + (size_t)brow * ((size_t)Tv * NG);
    float pi = acc[0][r] + bf2f(zrow[0 * Hv + j]);
    float pf = acc[1][r] + bf2f(zrow[1 * Hv + j]);
    float pg = acc[2][r] + bf2f(zrow[2 * Hv + j]);
    float po = acc[3][r] + bf2f(zrow[3 * Hv + j]);
    float ig = fsig(pi), fg = fsig(pf), gg = ftanh(pg), og = fsig(po);
    size_t ci = (size_t)brow * Hv + j;
    float cn = fg * cbuf[ci] + ig * gg;
    cbuf[ci] = cn;
    float h = og * ftanh(cn);
    hcur[ci] = f2bf(h);
    if (!last){
      dst_bf[((size_t)brow * Tv + t) * Hv + j] = f2bf(h);
    } else {
      out_h[((size_t)brow * Tv + t) * Hv + j] = h;
      out_c[((size_t)t * Bv + brow) * Hv + j] = cn;
    }
  }
}

// ---------------- host ----------------

extern "C" void kernel_launch(void* const* d_in, const int* in_sizes, int n_in,
                              void* d_out, int out_size, void* d_ws, size_t ws_size,
                              hipStream_t stream){
  const float* x = (const float*)d_in[0];
  // per layer pointers: 1 + l*12 + gate*3 + {0:W,1:U,2:b}, gates i,f,g,o
  const float *W[3][4], *U[3][4], *bb[3][4];
  for (int l = 0; l < 3; ++l)
    for (int g = 0; g < 4; ++g){
      W[l][g]  = (const float*)d_in[1 + l * 12 + g * 3 + 0];
      U[l][g]  = (const float*)d_in[1 + l * 12 + g * 3 + 1];
      bb[l][g] = (const float*)d_in[1 + l * 12 + g * 3 + 2];
    }

  char* ws = (char*)d_ws;
  u16* Zbf  = (u16*)ws;                                  // 256 MB
  u16* Xb0  = (u16*)(ws + 268435456ull);                 // 64 MB
  u16* Xb1  = (u16*)(ws + 335544320ull);                 // 64 MB
  u16* xbf  = (u16*)(ws + 402653184ull);                 // 32 MB
  u16* Wp[3] = { (u16*)(ws + 436207616ull),
                 (u16*)(ws + 440401920ull),
                 (u16*)(ws + 448790528ull) };
  u16* Up[3] = { (u16*)(ws + 457179136ull),
                 (u16*)(ws + 465567744ull),
                 (u16*)(ws + 473956352ull) };
  float* bias[3] = { (float*)(ws + 482344960ull),
                     (float*)(ws + 482361344ull),
                     (float*)(ws + 482377728ull) };
  float* cbuf = (float*)(ws + 482394112ull);             // 512 KB
  u16* hA = (u16*)(ws + 482918400ull);                   // 256 KB
  u16* hB = (u16*)(ws + 483180544ull);                   // 256 KB

  float* out_h = (float*)d_out;
  float* out_c = out_h + (size_t)Bv * Tv * Hv;

  // x -> bf16 (32768 x 512)
  cvt_f32_bf16<<<dim3(16384), dim3(256), 0, stream>>>(x, xbf, (Bv * Tv * Dv) / 4);

  // pack weights (bf16, MFMA B-frag layout) + biases
  for (int l = 0; l < 3; ++l){
    int K = (l == 0) ? Dv : Hv;
    int KT = K >> 5;
    int ntshift = (K == Dv) ? 13 : 14;     // log2(KT*512)
    pack_b<<<dim3((NG * K) / 256), dim3(256), 0, stream>>>(
        W[l][0], W[l][1], W[l][2], W[l][3], Wp[l], KT - 1, ntshift);
    pack_b<<<dim3((NG * Hv) / 256), dim3(256), 0, stream>>>(
        U[l][0], U[l][1], U[l][2], U[l][3], Up[l], (Hv >> 5) - 1, 14);
    pack_bias<<<dim3(16), dim3(256), 0, stream>>>(
        bb[l][0], bb[l][1], bb[l][2], bb[l][3], bias[l]);
  }

  const u16* Ain[3] = { xbf, Xb0, Xb1 };
  const int  Kl[3]  = { Dv, Hv, Hv };

  for (int l = 0; l < 3; ++l){
    hipMemsetAsync(cbuf, 0, (size_t)Bv * Hv * 4, stream);
    hipMemsetAsync(hA, 0, (size_t)Bv * Hv * 2, stream);

    pregemm<<<dim3(64, 256), dim3(256), 0, stream>>>(Ain[l], Wp[l], bias[l], Zbf, Kl[l]);

    u16* dst_bf = (l == 0) ? Xb0 : (l == 1) ? Xb1 : nullptr;
    for (int t = 0; t < Tv; ++t){
      const u16* hp = (t & 1) ? hB : hA;
      u16*       hc = (t & 1) ? hA : hB;
      lstm_step<<<dim3(64, 2), dim3(256), 0, stream>>>(
          hp, Up[l], Zbf + (size_t)t * NG, cbuf, hc, dst_bf, out_h, out_c, t, (l == 2) ? 1 : 0);
    }
  }
}